// Round 12
// baseline (124.641 us; speedup 1.0000x reference)
//
#include <hip/hip_runtime.h>
#include <hip/hip_bf16.h>

#define DIM 1024
#define HEADS 16
#define DH 64
#define SEQ 2048
#define BATCH 2
#define ROWS (BATCH*SEQ)
#define C3 (3*DIM)
#define NT (SEQ/64)

typedef __attribute__((ext_vector_type(8))) short s16x8;
typedef __attribute__((ext_vector_type(4))) short s16x4;
typedef __attribute__((ext_vector_type(4))) float f32x4;
typedef __attribute__((ext_vector_type(16))) float f32x16;
typedef __attribute__((ext_vector_type(4))) unsigned int u32x4;
typedef __attribute__((ext_vector_type(2))) unsigned int u32x2;

__device__ __forceinline__ void gll16(const void* g, void* l) {
  __builtin_amdgcn_global_load_lds((const __attribute__((address_space(1))) void*)g,
                                   (__attribute__((address_space(3))) void*)l, 16, 0, 0);
}
__device__ __forceinline__ float bf2f(short s) {
  return __builtin_bit_cast(float, ((unsigned)(unsigned short)s) << 16);
}
__device__ __forceinline__ short f2bf(float f) {
  return (short)__bfloat16_as_ushort(__float2bfloat16(f));
}
__device__ __forceinline__ unsigned pk2(float a, float b) {
  unsigned lo = (unsigned)__bfloat16_as_ushort(__float2bfloat16(a));
  unsigned hh = (unsigned)__bfloat16_as_ushort(__float2bfloat16(b));
  return lo | (hh << 16);
}
__device__ __forceinline__ float fexp2(float x) {
#if __has_builtin(__builtin_amdgcn_exp2f)
  return __builtin_amdgcn_exp2f(x);
#else
  float r; asm("v_exp_f32 %0, %1" : "=v"(r) : "v"(x)); return r;
#endif
}

// ---------------- Fused prep: LN (blocks 0..4095), W_qkv transpose (next 3072),
// ---------------- W_out transpose (next 1024). ----------
__global__ __launch_bounds__(256) void prep_kernel(const float* __restrict__ x,
    const float* __restrict__ gamma, const float* __restrict__ beta,
    __hip_bfloat16* __restrict__ xn,
    const float* __restrict__ Wqkv, __hip_bfloat16* __restrict__ wqkv_t,
    const float* __restrict__ Wout, __hip_bfloat16* __restrict__ wout_t) {
  const int bid = blockIdx.x;
  const int t = threadIdx.x;
  if (bid < ROWS) {
    __shared__ float red[8];
    const float4* xp = (const float4*)(x + (size_t)bid * DIM);
    float4 v = xp[t];
    float s = v.x + v.y + v.z + v.w;
    float q = v.x*v.x + v.y*v.y + v.z*v.z + v.w*v.w;
    for (int off = 32; off >= 1; off >>= 1) {
      s += __shfl_xor(s, off, 64);
      q += __shfl_xor(q, off, 64);
    }
    int w = t >> 6;
    if ((t & 63) == 0) { red[w] = s; red[4 + w] = q; }
    __syncthreads();
    s = red[0] + red[1] + red[2] + red[3];
    q = red[4] + red[5] + red[6] + red[7];
    float mu = s * (1.0f / DIM);
    float var = q * (1.0f / DIM) - mu * mu;
    float rstd = rsqrtf(var + 1e-5f);
    float4 g4 = ((const float4*)gamma)[t];
    float4 b4 = ((const float4*)beta)[t];
    __hip_bfloat16* op = xn + (size_t)bid * DIM + t * 4;
    op[0] = __float2bfloat16((v.x - mu) * rstd * g4.x + b4.x);
    op[1] = __float2bfloat16((v.y - mu) * rstd * g4.y + b4.y);
    op[2] = __float2bfloat16((v.z - mu) * rstd * g4.z + b4.z);
    op[3] = __float2bfloat16((v.w - mu) * rstd * g4.w + b4.w);
  } else {
    __shared__ float tile[32][33];
    const float* in; __hip_bfloat16* out; int R, Cn, c0, r0;
    if (bid < ROWS + 3072) {
      int id = bid - ROWS;
      in = Wqkv; out = wqkv_t; R = DIM; Cn = C3;
      c0 = (id % 96) * 32; r0 = (id / 96) * 32;
    } else {
      int id = bid - ROWS - 3072;
      in = Wout; out = wout_t; R = DIM; Cn = DIM;
      c0 = (id % 32) * 32; r0 = (id / 32) * 32;
    }
    int tx = t & 31, ty = t >> 5;
#pragma unroll
    for (int i = 0; i < 4; i++)
      tile[ty + i * 8][tx] = in[(size_t)(r0 + ty + i * 8) * Cn + c0 + tx];
    __syncthreads();
#pragma unroll
    for (int i = 0; i < 4; i++)
      out[(size_t)(c0 + ty + i * 8) * R + r0 + tx] = __float2bfloat16(tile[tx][ty + i * 8]);
  }
}

// ---------------- QKV GEMM 256x192, 8 waves, BK=64, dbuf + counted vmcnt,
// ---------------- 32x32x16 MFMA (wave tile 64x96), 2-phase split. 1 block/CU. ----------
__global__ __launch_bounds__(512) void gemm192(const __hip_bfloat16* __restrict__ A,
    const __hip_bfloat16* __restrict__ Bt, __hip_bfloat16* __restrict__ C,
    int M, int Nc, int K) {
  __shared__ short lds_a[2][256 * 64];   // 64 KiB
  __shared__ short lds_b[2][192 * 64];   // 48 KiB
  const int t = threadIdx.x, l = t & 63;
  const int w = t >> 6, wr = w >> 1, wc = w & 1;   // 4x2 waves: 64-row x 96-col tiles
  const int hi = l >> 5;
  const int m0 = blockIdx.y * 256, n0 = blockIdx.x * 192;
  const short* Ab = (const short*)A;
  const short* Bb = (const short*)Bt;
  f32x16 acc[2][3] = {};                 // 96 VGPR accumulator
  const int srow = t >> 3;
  const int schk = (t & 7) ^ (srow & 7);
  const int NIT = K / 64;

  {
    char* la = (char*)&lds_a[0][0];
    char* lb = (char*)&lds_b[0][0];
#pragma unroll
    for (int p = 0; p < 4; p++)
      gll16(Ab + (size_t)(m0 + p * 64 + srow) * K + schk * 8, la + p * 8192 + t * 16);
#pragma unroll
    for (int p = 0; p < 3; p++)
      gll16(Bb + (size_t)(n0 + p * 64 + srow) * K + schk * 8, lb + p * 8192 + t * 16);
  }
  for (int it = 0; it < NIT; ++it) {
    const int cur = it & 1;
    __syncthreads();
    if (it + 1 < NIT) {
      const int kk = (it + 1) * 64;
      char* la = (char*)&lds_a[cur ^ 1][0];
      char* lb = (char*)&lds_b[cur ^ 1][0];
#pragma unroll
      for (int p = 0; p < 4; p++)
        gll16(Ab + (size_t)(m0 + p * 64 + srow) * K + kk + schk * 8, la + p * 8192 + t * 16);
#pragma unroll
      for (int p = 0; p < 3; p++)
        gll16(Bb + (size_t)(n0 + p * 64 + srow) * K + kk + schk * 8, lb + p * 8192 + t * 16);
      asm volatile("s_waitcnt vmcnt(7)" ::: "memory");
    } else {
      asm volatile("s_waitcnt vmcnt(0)" ::: "memory");
    }
    __syncthreads();
    const char* la = (const char*)&lds_a[cur][0];
    const char* lb = (const char*)&lds_b[cur][0];
#pragma unroll
    for (int p = 0; p < 2; p++) {        // 2 phases x 2 k-steps (K=16 each)
      s16x8 af[2][2], bf[2][3];
#pragma unroll
      for (int k2 = 0; k2 < 2; k2++) {
        int g = 2 * (p * 2 + k2) + hi;   // granule 0..7
        int chk = (g ^ (l & 7)) * 16;
#pragma unroll
        for (int rb = 0; rb < 2; rb++)
          af[k2][rb] = *(const s16x8*)(la + (wr * 64 + rb * 32 + (l & 31)) * 128 + chk);
#pragma unroll
        for (int nn = 0; nn < 3; nn++)
          bf[k2][nn] = *(const s16x8*)(lb + (wc * 96 + nn * 32 + (l & 31)) * 128 + chk);
      }
      __builtin_amdgcn_s_barrier();
      asm volatile("s_waitcnt lgkmcnt(0)" ::: "memory");
      __builtin_amdgcn_sched_barrier(0);
      __builtin_amdgcn_s_setprio(1);
#pragma unroll
      for (int k2 = 0; k2 < 2; k2++)
#pragma unroll
        for (int rb = 0; rb < 2; rb++)
#pragma unroll
          for (int nn = 0; nn < 3; nn++)
            acc[rb][nn] = __builtin_amdgcn_mfma_f32_32x32x16_bf16(
                af[k2][rb], bf[k2][nn], acc[rb][nn], 0, 0, 0);
      __builtin_amdgcn_s_setprio(0);
      __builtin_amdgcn_s_barrier();
    }
  }
  // epilogue: C/D map col=l&31, row=(r&3)+8*(r>>2)+4*hi
#pragma unroll
  for (int rb = 0; rb < 2; rb++)
#pragma unroll
    for (int nn = 0; nn < 3; nn++) {
      int col = n0 + wc * 96 + nn * 32 + (l & 31);
#pragma unroll
      for (int r = 0; r < 16; r++) {
        int row = m0 + wr * 64 + rb * 32 + (r & 3) + 8 * (r >> 2) + 4 * hi;
        C[(size_t)row * Nc + col] = __float2bfloat16(acc[rb][nn][r]);
      }
    }
}

// ---------------- Out-proj GEMM 128x64, dbuf + counted vmcnt, fused bias, f32 out ----------
__global__ __launch_bounds__(256) void gemm_out(const __hip_bfloat16* __restrict__ A,
    const __hip_bfloat16* __restrict__ Bt, float* __restrict__ C,
    const float* __restrict__ bias) {
  __shared__ short lds_a[2][128 * 32];
  __shared__ short lds_b[2][64 * 32];
  const int t = threadIdx.x, l = t & 63, w = t >> 6;
  const int wr = w >> 1, wc = w & 1;
  const int m0 = blockIdx.y * 128, n0 = blockIdx.x * 64;
  const short* Ab = (const short*)A;
  const short* Bb = (const short*)Bt;
  const int K = DIM;
  f32x4 acc[4][2] = {};
  const int srow = t >> 2, scol = (t & 3) * 8;
  {
    char* la = (char*)&lds_a[0][0];
    char* lb = (char*)&lds_b[0][0];
    gll16(Ab + (size_t)(m0 + srow) * K + scol,      la + t * 16);
    gll16(Ab + (size_t)(m0 + 64 + srow) * K + scol, la + 4096 + t * 16);
    gll16(Bb + (size_t)(n0 + srow) * K + scol,      lb + t * 16);
  }
  for (int it = 0; it < K / 32; ++it) {
    const int cur = it & 1;
    __syncthreads();
    if (it + 1 < K / 32) {
      const int kk = (it + 1) * 32;
      char* la = (char*)&lds_a[cur ^ 1][0];
      char* lb = (char*)&lds_b[cur ^ 1][0];
      gll16(Ab + (size_t)(m0 + srow) * K + kk + scol,      la + t * 16);
      gll16(Ab + (size_t)(m0 + 64 + srow) * K + kk + scol, la + 4096 + t * 16);
      gll16(Bb + (size_t)(n0 + srow) * K + kk + scol,      lb + t * 16);
      asm volatile("s_waitcnt vmcnt(3)" ::: "memory");
    } else {
      asm volatile("s_waitcnt vmcnt(0)" ::: "memory");
    }
    __syncthreads();
    s16x8 af[4], bf[2];
#pragma unroll
    for (int m = 0; m < 4; m++)
      af[m] = *(const s16x8*)&lds_a[cur][(wr * 64 + m * 16 + (l & 15)) * 32 + (l >> 4) * 8];
#pragma unroll
    for (int n = 0; n < 2; n++)
      bf[n] = *(const s16x8*)&lds_b[cur][(wc * 32 + n * 16 + (l & 15)) * 32 + (l >> 4) * 8];
#pragma unroll
    for (int m = 0; m < 4; m++)
#pragma unroll
      for (int n = 0; n < 2; n++)
        acc[m][n] = __builtin_amdgcn_mfma_f32_16x16x32_bf16(af[m], bf[n], acc[m][n], 0, 0, 0);
  }
#pragma unroll
  for (int m = 0; m < 4; m++)
#pragma unroll
    for (int n = 0; n < 2; n++) {
      int col = n0 + wc * 32 + n * 16 + (l & 15);
      float bb = bias[col];
#pragma unroll
      for (int r = 0; r < 4; r++) {
        int row = m0 + wr * 64 + m * 16 + (l >> 4) * 4 + r;
        C[(size_t)row * DIM + col] = acc[m][n][r] + bb;
      }
    }
}

// ---------------- Flash attention v9: 4-wave blocks, 2 blocks/CU ----------------
// 512 blocks (2/CU -> two independent barrier domains per CU hide drain stalls).
// KVBLK=128, XCD head binding, static softmax, swapped QK^T, permlane P exchange,
// ones-column MFMA denominator.
__global__ __launch_bounds__(256) void attn_kernel(const __hip_bfloat16* __restrict__ qkv,
    __hip_bfloat16* __restrict__ attno) {
  const int t = threadIdx.x, l = t & 63, w = t >> 6;   // 4 waves
  const int hi = l >> 5, lq = l & 31;
  const int bid = blockIdx.x;                          // 0..511
  const int xcd = bid & 7, j = bid >> 3;               // j 0..63
  const int bh = xcd + 8 * (j & 3);                    // 0..31 (4 heads per XCD)
  const int qb = j >> 2;                               // 0..15
  const int b = bh >> 4, h = bh & 15;
  const short* base  = (const short*)qkv + (size_t)b * SEQ * C3 + h * DH;
  const short* kbase = base + DIM;
  const short* vbase = base + 2 * DIM;
  const int qr0 = qb * 128 + w * 32;

  __shared__ short kbuf[2][2][64 * 64];   // 32 KiB
  __shared__ short vbuf[2][2][64 * 64];   // 32 KiB

  // Q prescaled by 0.125 * log2(e)
  const float SCL = 0.125f * 1.44269504089f;
  s16x8 qf[4];
#pragma unroll
  for (int dk = 0; dk < 4; dk++) {
    s16x8 raw = *(const s16x8*)(base + (size_t)(qr0 + lq) * C3 + dk * 16 + hi * 8);
#pragma unroll
    for (int j2 = 0; j2 < 8; j2++) qf[dk][j2] = f2bf(bf2f(raw[j2]) * SCL);
  }

  s16x8 ones;
#pragma unroll
  for (int j2 = 0; j2 < 8; j2++) ones[j2] = (short)0x3F80;  // bf16 1.0

  f32x16 o0, o1, osum, zf;
#pragma unroll
  for (int r = 0; r < 16; r++) { o0[r] = 0.f; o1[r] = 0.f; osum[r] = 0.f; zf[r] = 0.f; }
  asm volatile("" : "+v"(zf));

  const int krow = t >> 3;                   // 0..31 (256 threads)
  const int ksrc = (t & 7) ^ (krow & 7);     // involution swizzle
  const int vr = t & 31, vc = (t >> 5) * 8;  // kv-pair 0..31, d-chunk 0..56

#define K_STAGE(DST, ROW0)                                                      \
  { char* kd_ = (char*)(DST);                                                   \
    gll16(kbase + (size_t)((ROW0) + krow) * C3 + ksrc * 8,      kd_ + t * 16);  \
    gll16(kbase + (size_t)((ROW0) + 32 + krow) * C3 + ksrc * 8, kd_ + 4096 + t * 16); }

#define V_LOAD(VA, VB, ROW0)                                                    \
  VA = __builtin_bit_cast(u32x4, *(const s16x8*)(vbase + (size_t)((ROW0) + 2 * vr) * C3 + vc)); \
  VB = __builtin_bit_cast(u32x4, *(const s16x8*)(vbase + (size_t)((ROW0) + 2 * vr + 1) * C3 + vc));

#define V_WRITE(VD, VA, VB)                                                     \
  { char* vd_ = (char*)(VD);                                                    \
    _Pragma("unroll")                                                           \
    for (int i = 0; i < 8; i++) {                                               \
      int d = vc + i;                                                           \
      unsigned dw = __builtin_amdgcn_perm((VB)[i >> 1], (VA)[i >> 1],           \
                                          (i & 1) ? 0x07060302u : 0x05040100u); \
      *(unsigned*)(vd_ + d * 128 + (((vr >> 2) ^ (d & 7)) * 16) + (vr & 3) * 4) = dw; } }

  // prologue: stage iteration 0 (both subtiles) into buf 0
  {
    K_STAGE(&kbuf[0][0][0], 0)
    K_STAGE(&kbuf[0][1][0], 64)
    u32x4 va0, vb0, va1, vb1;
    V_LOAD(va0, vb0, 0)
    V_LOAD(va1, vb1, 64)
    V_WRITE(&vbuf[0][0][0], va0, vb0)
    V_WRITE(&vbuf[0][1][0], va1, vb1)
  }
  __syncthreads();

#define ATTN_SUB(KB, VB)                                                        \
  {                                                                             \
    const char* kb_ = (const char*)(KB);                                        \
    const char* vbp_ = (const char*)(VB);                                       \
    f32x16 st0, st1;                                                            \
    { int chk0 = (hi ^ (l & 7)) * 16;                                           \
      s16x8 kf0 = *(const s16x8*)(kb_ + (size_t)lq * 128 + chk0);               \
      s16x8 kf1 = *(const s16x8*)(kb_ + (size_t)(32 + lq) * 128 + chk0);        \
      st0 = __builtin_amdgcn_mfma_f32_32x32x16_bf16(kf0, qf[0], zf, 0, 0, 0);   \
      st1 = __builtin_amdgcn_mfma_f32_32x32x16_bf16(kf1, qf[0], zf, 0, 0, 0); } \
    _Pragma("unroll")                                                           \
    for (int dk = 1; dk < 4; dk++) {                                            \
      int chk = ((2 * dk + hi) ^ (l & 7)) * 16;                                 \
      s16x8 kf0 = *(const s16x8*)(kb_ + (size_t)lq * 128 + chk);                \
      s16x8 kf1 = *(const s16x8*)(kb_ + (size_t)(32 + lq) * 128 + chk);         \
      st0 = __builtin_amdgcn_mfma_f32_32x32x16_bf16(kf0, qf[dk], st0, 0, 0, 0); \
      st1 = __builtin_amdgcn_mfma_f32_32x32x16_bf16(kf1, qf[dk], st1, 0, 0, 0); \
    }                                                                           \
    _Pragma("unroll")                                                           \
    for (int r = 0; r < 16; r++) { st0[r] = fexp2(st0[r]); st1[r] = fexp2(st1[r]); } \
    _Pragma("unroll")                                                           \
    for (int n = 0; n < 2; n++) {                                               \
      const f32x16& stn = n ? st1 : st0;                                        \
      _Pragma("unroll")                                                         \
      for (int ksl = 0; ksl < 2; ksl++) {                                       \
        int rb = ksl * 8;                                                       \
        int a_ = (int)pk2(stn[rb + 0], stn[rb + 1]);                            \
        int b_ = (int)pk2(stn[rb + 2], stn[rb + 3]);                            \
        int c_ = (int)pk2(stn[rb + 4], stn[rb + 5]);                            \
        int d_ = (int)pk2(stn[rb + 6], stn[rb + 7]);                            \
        asm volatile("v_permlane32_swap_b32 %0, %1" : "+v"(a_), "+v"(c_));      \
        asm volatile("v_permlane32_swap_b32 %0, %1" : "+v"(b_), "+v"(d_));      \
        u32x4 fr;                                                               \
        fr.x = (unsigned)a_;  fr.y = (unsigned)b_;                              \
        fr.z = (unsigned)c_;  fr.w = (unsigned)d_;                              \
        s16x8 pa = __builtin_bit_cast(s16x8, fr);                               \
        int ks = n * 2 + ksl;                                                   \
        int chk = ((2 * ks + hi) ^ (l & 7)) * 16;                               \
        s16x8 vf0 = *(const s16x8*)(vbp_ + (size_t)lq * 128 + chk);             \
        s16x8 vf1 = *(const s16x8*)(vbp_ + (size_t)(32 + lq) * 128 + chk);      \
        o0   = __builtin_amdgcn_mfma_f32_32x32x16_bf16(pa, vf0, o0, 0, 0, 0);   \
        o1   = __builtin_amdgcn_mfma_f32_32x32x16_bf16(pa, vf1, o1, 0, 0, 0);   \
        osum = __builtin_amdgcn_mfma_f32_32x32x16_bf16(pa, ones, osum, 0, 0, 0);\
      }                                                                         \
    }                                                                           \
  }

  for (int it = 0; it < NT / 2; ++it) {
    const int cur = it & 1;
    const bool pf = (it + 1 < NT / 2);
    u32x4 va0, vb0, va1, vb1;
    if (pf) {
      const int kv1 = (it + 1) * 128;
      K_STAGE(&kbuf[cur ^ 1][0][0], kv1)
      K_STAGE(&kbuf[cur ^ 1][1][0], kv1 + 64)
      V_LOAD(va0, vb0, kv1)
      V_LOAD(va1, vb1, kv1 + 64)
    }
    ATTN_SUB(&kbuf[cur][0][0], &vbuf[cur][0][0])
    ATTN_SUB(&kbuf[cur][1][0], &vbuf[cur][1][0])
    if (pf) {
      V_WRITE(&vbuf[cur ^ 1][0][0], va0, vb0)
      V_WRITE(&vbuf[cur ^ 1][1][0], va1, vb1)
    }
    __syncthreads();
  }
#undef ATTN_SUB
#undef K_STAGE
#undef V_LOAD
#undef V_WRITE

  // ---- epilogue ----
#pragma unroll
  for (int r = 0; r < 16; r++) {
    int qr = (r & 3) + 8 * (r >> 2) + 4 * hi;
    float ir = 1.0f / osum[r];
    size_t rowoff = (size_t)(b * SEQ + qr0 + qr) * DIM + h * DH;
    attno[rowoff + lq]      = __float2bfloat16(o0[r] * ir);
    attno[rowoff + 32 + lq] = __float2bfloat16(o1[r] * ir);
  }
}

extern "C" void kernel_launch(void* const* d_in, const int* in_sizes, int n_in,
                              void* d_out, int out_size, void* d_ws, size_t ws_size,
                              hipStream_t stream) {
  const float* x     = (const float*)d_in[0];
  const float* gamma = (const float*)d_in[1];
  const float* beta  = (const float*)d_in[2];
  const float* Wqkv  = (const float*)d_in[3];
  const float* Wout  = (const float*)d_in[4];
  const float* bout  = (const float*)d_in[5];

  __hip_bfloat16* xn     = (__hip_bfloat16*)d_ws;
  __hip_bfloat16* wqkv_t = xn + (size_t)ROWS * DIM;        // [3072][1024]
  __hip_bfloat16* wout_t = wqkv_t + (size_t)C3 * DIM;      // [1024][1024]
  __hip_bfloat16* qkv    = wout_t + (size_t)DIM * DIM;     // [4096][3072]
  __hip_bfloat16* attno  = qkv + (size_t)ROWS * C3;        // [4096][1024]

  prep_kernel<<<ROWS + 3072 + 1024, 256, 0, stream>>>(x, gamma, beta, xn,
                                                      Wqkv, wqkv_t, Wout, wout_t);
  gemm192<<<dim3(C3 / 192, ROWS / 256), 512, 0, stream>>>(xn, wqkv_t, qkv, ROWS, C3, DIM);
  attn_kernel<<<16 * BATCH * HEADS, 256, 0, stream>>>(qkv, attno);
  gemm_out<<<dim3(DIM / 64, ROWS / 128), 256, 0, stream>>>(attno, wout_t, (float*)d_out, bout);
}

// Round 13
// 118.311 us; speedup vs baseline: 1.0535x; 1.0535x over previous
//
#include <hip/hip_runtime.h>
#include <hip/hip_bf16.h>

#define DIM 1024
#define HEADS 16
#define DH 64
#define SEQ 2048
#define BATCH 2
#define ROWS (BATCH*SEQ)
#define C3 (3*DIM)
#define NT (SEQ/64)

typedef __attribute__((ext_vector_type(8))) short s16x8;
typedef __attribute__((ext_vector_type(4))) short s16x4;
typedef __attribute__((ext_vector_type(4))) float f32x4;
typedef __attribute__((ext_vector_type(16))) float f32x16;
typedef __attribute__((ext_vector_type(4))) unsigned int u32x4;
typedef __attribute__((ext_vector_type(2))) unsigned int u32x2;

__device__ __forceinline__ void gll16(const void* g, void* l) {
  __builtin_amdgcn_global_load_lds((const __attribute__((address_space(1))) void*)g,
                                   (__attribute__((address_space(3))) void*)l, 16, 0, 0);
}
__device__ __forceinline__ float bf2f(short s) {
  return __builtin_bit_cast(float, ((unsigned)(unsigned short)s) << 16);
}
__device__ __forceinline__ short f2bf(float f) {
  return (short)__bfloat16_as_ushort(__float2bfloat16(f));
}
__device__ __forceinline__ unsigned pk2(float a, float b) {
  unsigned lo = (unsigned)__bfloat16_as_ushort(__float2bfloat16(a));
  unsigned hh = (unsigned)__bfloat16_as_ushort(__float2bfloat16(b));
  return lo | (hh << 16);
}
__device__ __forceinline__ float fexp2(float x) {
#if __has_builtin(__builtin_amdgcn_exp2f)
  return __builtin_amdgcn_exp2f(x);
#else
  float r; asm("v_exp_f32 %0, %1" : "=v"(r) : "v"(x)); return r;
#endif
}

// ---------------- Fused prep: LN (blocks 0..4095), W_qkv transpose (next 3072),
// ---------------- W_out transpose (next 1024). ----------
__global__ __launch_bounds__(256) void prep_kernel(const float* __restrict__ x,
    const float* __restrict__ gamma, const float* __restrict__ beta,
    __hip_bfloat16* __restrict__ xn,
    const float* __restrict__ Wqkv, __hip_bfloat16* __restrict__ wqkv_t,
    const float* __restrict__ Wout, __hip_bfloat16* __restrict__ wout_t) {
  const int bid = blockIdx.x;
  const int t = threadIdx.x;
  if (bid < ROWS) {
    __shared__ float red[8];
    const float4* xp = (const float4*)(x + (size_t)bid * DIM);
    float4 v = xp[t];
    float s = v.x + v.y + v.z + v.w;
    float q = v.x*v.x + v.y*v.y + v.z*v.z + v.w*v.w;
    for (int off = 32; off >= 1; off >>= 1) {
      s += __shfl_xor(s, off, 64);
      q += __shfl_xor(q, off, 64);
    }
    int w = t >> 6;
    if ((t & 63) == 0) { red[w] = s; red[4 + w] = q; }
    __syncthreads();
    s = red[0] + red[1] + red[2] + red[3];
    q = red[4] + red[5] + red[6] + red[7];
    float mu = s * (1.0f / DIM);
    float var = q * (1.0f / DIM) - mu * mu;
    float rstd = rsqrtf(var + 1e-5f);
    float4 g4 = ((const float4*)gamma)[t];
    float4 b4 = ((const float4*)beta)[t];
    __hip_bfloat16* op = xn + (size_t)bid * DIM + t * 4;
    op[0] = __float2bfloat16((v.x - mu) * rstd * g4.x + b4.x);
    op[1] = __float2bfloat16((v.y - mu) * rstd * g4.y + b4.y);
    op[2] = __float2bfloat16((v.z - mu) * rstd * g4.z + b4.z);
    op[3] = __float2bfloat16((v.w - mu) * rstd * g4.w + b4.w);
  } else {
    __shared__ float tile[32][33];
    const float* in; __hip_bfloat16* out; int R, Cn, c0, r0;
    if (bid < ROWS + 3072) {
      int id = bid - ROWS;
      in = Wqkv; out = wqkv_t; R = DIM; Cn = C3;
      c0 = (id % 96) * 32; r0 = (id / 96) * 32;
    } else {
      int id = bid - ROWS - 3072;
      in = Wout; out = wout_t; R = DIM; Cn = DIM;
      c0 = (id % 32) * 32; r0 = (id / 32) * 32;
    }
    int tx = t & 31, ty = t >> 5;
#pragma unroll
    for (int i = 0; i < 4; i++)
      tile[ty + i * 8][tx] = in[(size_t)(r0 + ty + i * 8) * Cn + c0 + tx];
    __syncthreads();
#pragma unroll
    for (int i = 0; i < 4; i++)
      out[(size_t)(c0 + ty + i * 8) * R + r0 + tx] = __float2bfloat16(tile[tx][ty + i * 8]);
  }
}

// ---------------- QKV GEMM 256x192, 8 waves, BK=64, dbuf + counted vmcnt,
// ---------------- 4-phase compute split. 1 block/CU. (round-11 verified) ----------
__global__ __launch_bounds__(512) void gemm192(const __hip_bfloat16* __restrict__ A,
    const __hip_bfloat16* __restrict__ Bt, __hip_bfloat16* __restrict__ C,
    int M, int Nc, int K) {
  __shared__ short lds_a[2][256 * 64];   // 64 KiB
  __shared__ short lds_b[2][192 * 64];   // 48 KiB
  const int t = threadIdx.x, l = t & 63;
  const int w = t >> 6, wr = w >> 2, wc = w & 3;
  const int m0 = blockIdx.y * 256, n0 = blockIdx.x * 192;
  const short* Ab = (const short*)A;
  const short* Bb = (const short*)Bt;
  f32x4 acc[8][3] = {};
  const int srow = t >> 3;
  const int schk = (t & 7) ^ (srow & 7);
  const int NIT = K / 64;

  {
    char* la = (char*)&lds_a[0][0];
    char* lb = (char*)&lds_b[0][0];
#pragma unroll
    for (int p = 0; p < 4; p++)
      gll16(Ab + (size_t)(m0 + p * 64 + srow) * K + schk * 8, la + p * 8192 + t * 16);
#pragma unroll
    for (int p = 0; p < 3; p++)
      gll16(Bb + (size_t)(n0 + p * 64 + srow) * K + schk * 8, lb + p * 8192 + t * 16);
  }
  for (int it = 0; it < NIT; ++it) {
    const int cur = it & 1;
    __syncthreads();
    if (it + 1 < NIT) {
      const int kk = (it + 1) * 64;
      char* la = (char*)&lds_a[cur ^ 1][0];
      char* lb = (char*)&lds_b[cur ^ 1][0];
#pragma unroll
      for (int p = 0; p < 4; p++)
        gll16(Ab + (size_t)(m0 + p * 64 + srow) * K + kk + schk * 8, la + p * 8192 + t * 16);
#pragma unroll
      for (int p = 0; p < 3; p++)
        gll16(Bb + (size_t)(n0 + p * 64 + srow) * K + kk + schk * 8, lb + p * 8192 + t * 16);
      asm volatile("s_waitcnt vmcnt(7)" ::: "memory");
    } else {
      asm volatile("s_waitcnt vmcnt(0)" ::: "memory");
    }
    __syncthreads();
    const char* la = (const char*)&lds_a[cur][0];
    const char* lb = (const char*)&lds_b[cur][0];
    s16x8 af[4], bf[3];
#define GPH_READ_A(FH, S)                                                     \
    _Pragma("unroll")                                                         \
    for (int f = 0; f < 4; f++) {                                             \
      int row = wr * 128 + (FH * 4 + f) * 16 + (l & 15);                      \
      int chk = (((S) * 4 + (l >> 4)) ^ (l & 7)) * 16;                        \
      af[f] = *(const s16x8*)(la + row * 128 + chk);                          \
    }
#define GPH_READ_B(S)                                                         \
    _Pragma("unroll")                                                         \
    for (int n = 0; n < 3; n++) {                                             \
      int row = wc * 48 + n * 16 + (l & 15);                                  \
      int chk = (((S) * 4 + (l >> 4)) ^ (l & 7)) * 16;                        \
      bf[n] = *(const s16x8*)(lb + row * 128 + chk);                          \
    }
#define GPH_MFMA(FH)                                                          \
    __builtin_amdgcn_s_barrier();                                             \
    asm volatile("s_waitcnt lgkmcnt(0)" ::: "memory");                        \
    __builtin_amdgcn_sched_barrier(0);                                        \
    __builtin_amdgcn_s_setprio(1);                                            \
    _Pragma("unroll")                                                         \
    for (int f = 0; f < 4; f++)                                               \
      _Pragma("unroll")                                                       \
      for (int n = 0; n < 3; n++)                                             \
        acc[FH * 4 + f][n] =                                                  \
            __builtin_amdgcn_mfma_f32_16x16x32_bf16(af[f], bf[n],             \
                                                    acc[FH * 4 + f][n], 0, 0, 0); \
    __builtin_amdgcn_s_setprio(0);                                            \
    __builtin_amdgcn_s_barrier();

    GPH_READ_A(0, 0) GPH_READ_B(0) GPH_MFMA(0)
    GPH_READ_A(1, 0) GPH_MFMA(1)
    GPH_READ_A(0, 1) GPH_READ_B(1) GPH_MFMA(0)
    GPH_READ_A(1, 1) GPH_MFMA(1)
#undef GPH_READ_A
#undef GPH_READ_B
#undef GPH_MFMA
  }
#pragma unroll
  for (int f = 0; f < 8; f++)
#pragma unroll
    for (int n = 0; n < 3; n++) {
      int col = n0 + wc * 48 + n * 16 + (l & 15);
#pragma unroll
      for (int r = 0; r < 4; r++) {
        int row = m0 + wr * 128 + f * 16 + (l >> 4) * 4 + r;
        C[(size_t)row * Nc + col] = __float2bfloat16(acc[f][n][r]);
      }
    }
}

// ---------------- Out-proj GEMM 128x64, dbuf + counted vmcnt, fused bias, f32 out ----------
__global__ __launch_bounds__(256) void gemm_out(const __hip_bfloat16* __restrict__ A,
    const __hip_bfloat16* __restrict__ Bt, float* __restrict__ C,
    const float* __restrict__ bias) {
  __shared__ short lds_a[2][128 * 32];
  __shared__ short lds_b[2][64 * 32];
  const int t = threadIdx.x, l = t & 63, w = t >> 6;
  const int wr = w >> 1, wc = w & 1;
  const int m0 = blockIdx.y * 128, n0 = blockIdx.x * 64;
  const short* Ab = (const short*)A;
  const short* Bb = (const short*)Bt;
  const int K = DIM;
  f32x4 acc[4][2] = {};
  const int srow = t >> 2, scol = (t & 3) * 8;
  {
    char* la = (char*)&lds_a[0][0];
    char* lb = (char*)&lds_b[0][0];
    gll16(Ab + (size_t)(m0 + srow) * K + scol,      la + t * 16);
    gll16(Ab + (size_t)(m0 + 64 + srow) * K + scol, la + 4096 + t * 16);
    gll16(Bb + (size_t)(n0 + srow) * K + scol,      lb + t * 16);
  }
  for (int it = 0; it < K / 32; ++it) {
    const int cur = it & 1;
    __syncthreads();
    if (it + 1 < K / 32) {
      const int kk = (it + 1) * 32;
      char* la = (char*)&lds_a[cur ^ 1][0];
      char* lb = (char*)&lds_b[cur ^ 1][0];
      gll16(Ab + (size_t)(m0 + srow) * K + kk + scol,      la + t * 16);
      gll16(Ab + (size_t)(m0 + 64 + srow) * K + kk + scol, la + 4096 + t * 16);
      gll16(Bb + (size_t)(n0 + srow) * K + kk + scol,      lb + t * 16);
      asm volatile("s_waitcnt vmcnt(3)" ::: "memory");
    } else {
      asm volatile("s_waitcnt vmcnt(0)" ::: "memory");
    }
    __syncthreads();
    s16x8 af[4], bf[2];
#pragma unroll
    for (int m = 0; m < 4; m++)
      af[m] = *(const s16x8*)&lds_a[cur][(wr * 64 + m * 16 + (l & 15)) * 32 + (l >> 4) * 8];
#pragma unroll
    for (int n = 0; n < 2; n++)
      bf[n] = *(const s16x8*)&lds_b[cur][(wc * 32 + n * 16 + (l & 15)) * 32 + (l >> 4) * 8];
#pragma unroll
    for (int m = 0; m < 4; m++)
#pragma unroll
      for (int n = 0; n < 2; n++)
        acc[m][n] = __builtin_amdgcn_mfma_f32_16x16x32_bf16(af[m], bf[n], acc[m][n], 0, 0, 0);
  }
#pragma unroll
  for (int m = 0; m < 4; m++)
#pragma unroll
    for (int n = 0; n < 2; n++) {
      int col = n0 + wc * 32 + n * 16 + (l & 15);
      float bb = bias[col];
#pragma unroll
      for (int r = 0; r < 4; r++) {
        int row = m0 + wr * 64 + m * 16 + (l >> 4) * 4 + r;
        C[(size_t)row * DIM + col] = acc[m][n][r] + bb;
      }
    }
}

// ---------------- Flash attention v10: 8 waves, KVBLK=128, QK/PV software pipeline ----------
// Per iteration: QK(sub0); QK(sub1); {exp+PV}(sub0); {exp+PV}(sub1) — sub1's QK
// MFMAs fill sub0's exp/pack latency and vice versa (T15 pattern). XCD head
// binding, static softmax, permlane P exchange, ones-column MFMA denominator.
__global__ __launch_bounds__(512) void attn_kernel(const __hip_bfloat16* __restrict__ qkv,
    __hip_bfloat16* __restrict__ attno) {
  const int t = threadIdx.x, l = t & 63, w = t >> 6;
  const int hi = l >> 5, lq = l & 31;
  const int bid = blockIdx.x;
  const int xcd = bid & 7, j = bid >> 3;
  const int bh = xcd + 8 * (j & 3);      // 0..31 (4 heads per XCD)
  const int qb = j >> 2;                 // 0..7
  const int b = bh >> 4, h = bh & 15;
  const short* base  = (const short*)qkv + (size_t)b * SEQ * C3 + h * DH;
  const short* kbase = base + DIM;
  const short* vbase = base + 2 * DIM;
  const int qr0 = qb * 256 + w * 32;

  __shared__ short kbuf[2][2][64 * 64];   // 32 KiB
  __shared__ short vbuf[2][2][64 * 64];   // 32 KiB

  // Q prescaled by 0.125 * log2(e)
  const float SCL = 0.125f * 1.44269504089f;
  s16x8 qf[4];
#pragma unroll
  for (int dk = 0; dk < 4; dk++) {
    s16x8 raw = *(const s16x8*)(base + (size_t)(qr0 + lq) * C3 + dk * 16 + hi * 8);
#pragma unroll
    for (int j2 = 0; j2 < 8; j2++) qf[dk][j2] = f2bf(bf2f(raw[j2]) * SCL);
  }

  s16x8 ones;
#pragma unroll
  for (int j2 = 0; j2 < 8; j2++) ones[j2] = (short)0x3F80;  // bf16 1.0

  f32x16 o0, o1, osum, zf;
#pragma unroll
  for (int r = 0; r < 16; r++) { o0[r] = 0.f; o1[r] = 0.f; osum[r] = 0.f; zf[r] = 0.f; }
  asm volatile("" : "+v"(zf));

  const int krow = t >> 3;                   // 0..63
  const int ksrc = (t & 7) ^ (krow & 7);     // involution swizzle
  const int vr = t & 31, vcg = t >> 5;       // kv-pair 0..31, d-group 0..15

#define K_STAGE(DST, ROW0)                                                      \
  gll16(kbase + (size_t)((ROW0) + krow) * C3 + ksrc * 8, (char*)(DST) + t * 16);

#define V_LOAD(VA, VB, ROW0)                                                    \
  VA = __builtin_bit_cast(u32x2, *(const s16x4*)(vbase + (size_t)((ROW0) + 2 * vr) * C3 + vcg * 4)); \
  VB = __builtin_bit_cast(u32x2, *(const s16x4*)(vbase + (size_t)((ROW0) + 2 * vr + 1) * C3 + vcg * 4));

#define V_WRITE(VD, VA, VB)                                                     \
  { char* vd_ = (char*)(VD);                                                    \
    _Pragma("unroll")                                                           \
    for (int i = 0; i < 4; i++) {                                               \
      int d = vcg * 4 + i;                                                      \
      unsigned dw = __builtin_amdgcn_perm((VB)[i >> 1], (VA)[i >> 1],           \
                                          (i & 1) ? 0x07060302u : 0x05040100u); \
      *(unsigned*)(vd_ + d * 128 + (((vr >> 2) ^ (d & 7)) * 16) + (vr & 3) * 4) = dw; } }

  // prologue: stage iteration 0 (both subtiles) into buf 0
  {
    K_STAGE(&kbuf[0][0][0], 0)
    K_STAGE(&kbuf[0][1][0], 64)
    u32x2 va0, vb0, va1, vb1;
    V_LOAD(va0, vb0, 0)
    V_LOAD(va1, vb1, 64)
    V_WRITE(&vbuf[0][0][0], va0, vb0)
    V_WRITE(&vbuf[0][1][0], va1, vb1)
  }
  __syncthreads();

#define QK_SUB(KB, S0, S1)                                                      \
  {                                                                             \
    const char* kb_ = (const char*)(KB);                                        \
    { int chk0 = (hi ^ (l & 7)) * 16;                                           \
      s16x8 kf0 = *(const s16x8*)(kb_ + (size_t)lq * 128 + chk0);               \
      s16x8 kf1 = *(const s16x8*)(kb_ + (size_t)(32 + lq) * 128 + chk0);        \
      S0 = __builtin_amdgcn_mfma_f32_32x32x16_bf16(kf0, qf[0], zf, 0, 0, 0);    \
      S1 = __builtin_amdgcn_mfma_f32_32x32x16_bf16(kf1, qf[0], zf, 0, 0, 0); }  \
    _Pragma("unroll")                                                           \
    for (int dk = 1; dk < 4; dk++) {                                            \
      int chk = ((2 * dk + hi) ^ (l & 7)) * 16;                                 \
      s16x8 kf0 = *(const s16x8*)(kb_ + (size_t)lq * 128 + chk);                \
      s16x8 kf1 = *(const s16x8*)(kb_ + (size_t)(32 + lq) * 128 + chk);         \
      S0 = __builtin_amdgcn_mfma_f32_32x32x16_bf16(kf0, qf[dk], S0, 0, 0, 0);   \
      S1 = __builtin_amdgcn_mfma_f32_32x32x16_bf16(kf1, qf[dk], S1, 0, 0, 0);   \
    }                                                                           \
  }

#define SMPV_SUB(S0, S1, VB)                                                    \
  {                                                                             \
    const char* vbp_ = (const char*)(VB);                                       \
    _Pragma("unroll")                                                           \
    for (int r = 0; r < 16; r++) { S0[r] = fexp2(S0[r]); S1[r] = fexp2(S1[r]); }\
    _Pragma("unroll")                                                           \
    for (int n = 0; n < 2; n++) {                                               \
      const f32x16& stn = n ? S1 : S0;                                          \
      _Pragma("unroll")                                                         \
      for (int ksl = 0; ksl < 2; ksl++) {                                       \
        int rb = ksl * 8;                                                       \
        int a_ = (int)pk2(stn[rb + 0], stn[rb + 1]);                            \
        int b_ = (int)pk2(stn[rb + 2], stn[rb + 3]);                            \
        int c_ = (int)pk2(stn[rb + 4], stn[rb + 5]);                            \
        int d_ = (int)pk2(stn[rb + 6], stn[rb + 7]);                            \
        asm volatile("v_permlane32_swap_b32 %0, %1" : "+v"(a_), "+v"(c_));      \
        asm volatile("v_permlane32_swap_b32 %0, %1" : "+v"(b_), "+v"(d_));      \
        u32x4 fr;                                                               \
        fr.x = (unsigned)a_;  fr.y = (unsigned)b_;                              \
        fr.z = (unsigned)c_;  fr.w = (unsigned)d_;                              \
        s16x8 pa = __builtin_bit_cast(s16x8, fr);                               \
        int ks = n * 2 + ksl;                                                   \
        int chk = ((2 * ks + hi) ^ (l & 7)) * 16;                               \
        s16x8 vf0 = *(const s16x8*)(vbp_ + (size_t)lq * 128 + chk);             \
        s16x8 vf1 = *(const s16x8*)(vbp_ + (size_t)(32 + lq) * 128 + chk);      \
        o0   = __builtin_amdgcn_mfma_f32_32x32x16_bf16(pa, vf0, o0, 0, 0, 0);   \
        o1   = __builtin_amdgcn_mfma_f32_32x32x16_bf16(pa, vf1, o1, 0, 0, 0);   \
        osum = __builtin_amdgcn_mfma_f32_32x32x16_bf16(pa, ones, osum, 0, 0, 0);\
      }                                                                         \
    }                                                                           \
  }

  for (int it = 0; it < NT / 2; ++it) {
    const int cur = it & 1;
    const bool pf = (it + 1 < NT / 2);
    u32x2 va0, vb0, va1, vb1;
    if (pf) {
      const int kv1 = (it + 1) * 128;
      K_STAGE(&kbuf[cur ^ 1][0][0], kv1)
      K_STAGE(&kbuf[cur ^ 1][1][0], kv1 + 64)
      V_LOAD(va0, vb0, kv1)
      V_LOAD(va1, vb1, kv1 + 64)
    }
    f32x16 sa0, sa1, sb0, sb1;
    QK_SUB(&kbuf[cur][0][0], sa0, sa1)
    QK_SUB(&kbuf[cur][1][0], sb0, sb1)
    SMPV_SUB(sa0, sa1, &vbuf[cur][0][0])
    SMPV_SUB(sb0, sb1, &vbuf[cur][1][0])
    if (pf) {
      V_WRITE(&vbuf[cur ^ 1][0][0], va0, vb0)
      V_WRITE(&vbuf[cur ^ 1][1][0], va1, vb1)
    }
    __syncthreads();
  }
#undef QK_SUB
#undef SMPV_SUB
#undef K_STAGE
#undef V_LOAD
#undef V_WRITE

  // ---- epilogue ----
#pragma unroll
  for (int r = 0; r < 16; r++) {
    int qr = (r & 3) + 8 * (r >> 2) + 4 * hi;
    float ir = 1.0f / osum[r];
    size_t rowoff = (size_t)(b * SEQ + qr0 + qr) * DIM + h * DH;
    attno[rowoff + lq]      = __float2bfloat16(o0[r] * ir);
    attno[rowoff + 32 + lq] = __float2bfloat16(o1[r] * ir);
  }
}

extern "C" void kernel_launch(void* const* d_in, const int* in_sizes, int n_in,
                              void* d_out, int out_size, void* d_ws, size_t ws_size,
                              hipStream_t stream) {
  const float* x     = (const float*)d_in[0];
  const float* gamma = (const float*)d_in[1];
  const float* beta  = (const float*)d_in[2];
  const float* Wqkv  = (const float*)d_in[3];
  const float* Wout  = (const float*)d_in[4];
  const float* bout  = (const float*)d_in[5];

  __hip_bfloat16* xn     = (__hip_bfloat16*)d_ws;
  __hip_bfloat16* wqkv_t = xn + (size_t)ROWS * DIM;        // [3072][1024]
  __hip_bfloat16* wout_t = wqkv_t + (size_t)C3 * DIM;      // [1024][1024]
  __hip_bfloat16* qkv    = wout_t + (size_t)DIM * DIM;     // [4096][3072]
  __hip_bfloat16* attno  = qkv + (size_t)ROWS * C3;        // [4096][1024]

  prep_kernel<<<ROWS + 3072 + 1024, 256, 0, stream>>>(x, gamma, beta, xn,
                                                      Wqkv, wqkv_t, Wout, wout_t);
  gemm192<<<dim3(C3 / 192, ROWS / 256), 512, 0, stream>>>(xn, wqkv_t, qkv, ROWS, C3, DIM);
  attn_kernel<<<8 * BATCH * HEADS, 512, 0, stream>>>(qkv, attno);
  gemm_out<<<dim3(DIM / 64, ROWS / 128), 256, 0, stream>>>(attno, wout_t, (float*)d_out, bout);
}